// Round 8
// baseline (200.447 us; speedup 1.0000x reference)
//
#include <hip/hip_runtime.h>
#include <cmath>

// Shapes fixed by the reference: data [32,128,80,80] int32, scale 0.0625.
#define NB  32
#define NC  128
#define NHW 6400          // 80*80, contiguous per (b,c)
#define PIX 64            // pixels per block (K1 / mono)
#define TPB 256
#define NQ4 (NHW / 4)     // 1600 pixel-quads per image plane
#define NQUAD (NB * NQ4)  // 51200 pixel-quads total

typedef float vfloat4 __attribute__((ext_vector_type(4)));

// ---------------------------------------------------------------------------
// K1: champion structure, but stores only per-pixel-quad stats (qmax packed
// 4x int8 + recip float4) -> ~1 MB of writes instead of 102 MB.
// All reductions / LUT math are the champion's EXACT op order.
// ---------------------------------------------------------------------------
__global__ __launch_bounds__(TPB) void qsoftmax_stats_kernel(
    const int* __restrict__ data,
    const float* __restrict__ dscale,
    int* __restrict__ qp_ws,          // [NQUAD] packed qmax (4x int8)
    float4* __restrict__ rec_ws) {    // [NQUAD] recip per pixel of the quad
#pragma clang fp contract(off)
  __shared__ int   exp_tab[256];
  __shared__ float recip_tab[256];
  __shared__ int4  red_m[16][16];
  __shared__ int4  red_s[16][16];

  const int t  = threadIdx.x;
  const int k  = t >> 4;
  const int p4 = t & 15;

  const int blk  = blockIdx.x;
  const int b    = blk / (NHW / PIX);
  const int hw0  = (blk % (NHW / PIX)) * PIX;
  const int base4 = b * NC * NQ4 + (hw0 >> 2);

  const float ds = dscale[0];  // 0.0625

  // ---- build LUTs (champion-exact; do not touch) ----
  {
    const float EXP_SCALE_F = (float)(2.0 / 65535.0);
    float x = (float)(-t) * ds;
    float e;
    if (x >= 0.0f) {
      float y0 = expf(0.0f), y1 = expf(1.0f);
      e = rintf((y0 + x * ((y1 - y0) / 1.0f)) / EXP_SCALE_F);
    } else if (x >= -10.0f) {
      float delta = 10.0f / 255.0f;
      float idxf = rintf((x + 10.0f) * 25.5f);
      idxf = fminf(fmaxf(idxf, 0.0f), 255.0f);
      float xs = -10.0f + idxf * delta;
      e = rintf((float)exp((double)xs) / EXP_SCALE_F);
    } else {
      float delta = 10.0f / 255.0f;
      float idxf = rintf((x + 20.0f) * 25.5f);
      idxf = fminf(fmaxf(idxf, 0.0f), 255.0f);
      float xs = -20.0f + idxf * delta;
      e = rintf((float)exp((double)xs) / EXP_SCALE_F);
    }
    e = fminf(fmaxf(e, -32768.0f), 32767.0f);
    exp_tab[t] = (int)e;

    const float RECIP_SCALE_F = (float)((1.0 / 0.1) * 2.0 / 65535.0);
    float deltar = (250.0f - 0.1f) / 255.0f;
    float xs = 0.1f + (float)t * deltar;
    float r = rintf((1.0f / xs) / RECIP_SCALE_F);
    r = fminf(fmaxf(r, -32768.0f), 32767.0f);
    recip_tab[t] = r;
  }

  // ---- load 8 channels x 4 pixels; pack; local max (champion exact) ----
  const int4* g4 = (const int4*)data;
  int pd[8];
  int4 m = make_int4(-128, -128, -128, -128);
#pragma unroll
  for (int i = 0; i < 8; ++i) {
    int4 v = g4[base4 + (16 * i + k) * NQ4 + p4];
    m.x = max(m.x, v.x); m.y = max(m.y, v.y);
    m.z = max(m.z, v.z); m.w = max(m.w, v.w);
    pd[i] = (v.x & 255) | ((v.y & 255) << 8) | ((v.z & 255) << 16) |
            (int)((unsigned)(v.w & 255) << 24);
  }
  red_m[k][p4] = m;
  __syncthreads();

  int4 q = red_m[0][p4];
#pragma unroll
  for (int kk = 1; kk < 16; ++kk) {
    int4 r = red_m[kk][p4];
    q.x = max(q.x, r.x); q.y = max(q.y, r.y);
    q.z = max(q.z, r.z); q.w = max(q.w, r.w);
  }

  // ---- exp gather + channel partial sum (champion exact, pe[] dropped) ----
  int4 s = make_int4(0, 0, 0, 0);
#pragma unroll
  for (int i = 0; i < 8; ++i) {
    int pdv = pd[i];
    int c0 = (pdv << 24) >> 24;
    int c1 = (pdv << 16) >> 24;
    int c2 = (pdv << 8) >> 24;
    int c3 = pdv >> 24;
    s.x += exp_tab[q.x - c0];     // j guaranteed in [0,255]
    s.y += exp_tab[q.y - c1];
    s.z += exp_tab[q.z - c2];
    s.w += exp_tab[q.w - c3];
  }
  red_s[k][p4] = s;
  __syncthreads();

  int4 tot = red_s[0][p4];
#pragma unroll
  for (int kk = 1; kk < 16; ++kk) {
    int4 r = red_s[kk][p4];
    tot.x += r.x; tot.y += r.y; tot.z += r.z; tot.w += r.w;
  }
  const float DIV_SCALE_F = (float)((2.0 / 65535.0) * 128.0); // exp_scale*2^7
  const float RIDX_K_F    = (float)(255.0 / (250.0 - 0.1));
  float rq[4];
  {
    int tv[4] = {tot.x, tot.y, tot.z, tot.w};
#pragma unroll
    for (int j = 0; j < 4; ++j) {
      float ss = rintf((float)tv[j] * 0.0078125f);
      ss = fminf(fmaxf(ss, -32768.0f), 32767.0f);
      float v = ss * DIV_SCALE_F;
      float idxf = rintf((v - 0.1f) * RIDX_K_F);
      idxf = fminf(fmaxf(idxf, 0.0f), 255.0f);
      rq[j] = recip_tab[(int)idxf];
    }
  }

  // ---- store per-quad stats once (k==0 lanes only); tiny write volume ----
  if (k == 0) {
    const int sq = b * NQ4 + (hw0 >> 2) + p4;
    qp_ws[sq] = (q.x & 255) | ((q.y & 255) << 8) | ((q.z & 255) << 16) |
                (int)((unsigned)(q.w & 255) << 24);
    rec_ws[sq] = make_float4(rq[0], rq[1], rq[2], rq[3]);
  }
}

// ---------------------------------------------------------------------------
// K2: elementwise expand, LINEAR address walk. Dense int4 reads of data
// (L3-resident after K1), per-quad stats reads (L2-hot, reused across the
// 128 channels), dense NT float4 writes of the output.
// ---------------------------------------------------------------------------
__global__ __launch_bounds__(TPB) void qsoftmax_expand_kernel(
    const int* __restrict__ data,
    const float* __restrict__ dscale,
    const int* __restrict__ qp_ws,
    const float4* __restrict__ rec_ws,
    float* __restrict__ out) {
#pragma clang fp contract(off)
  __shared__ int exp_tab[256];

  const int t = threadIdx.x;
  const float ds = dscale[0];

  // ---- build exp LUT (champion-exact) ----
  {
    const float EXP_SCALE_F = (float)(2.0 / 65535.0);
    float x = (float)(-t) * ds;
    float e;
    if (x >= 0.0f) {
      float y0 = expf(0.0f), y1 = expf(1.0f);
      e = rintf((y0 + x * ((y1 - y0) / 1.0f)) / EXP_SCALE_F);
    } else if (x >= -10.0f) {
      float delta = 10.0f / 255.0f;
      float idxf = rintf((x + 10.0f) * 25.5f);
      idxf = fminf(fmaxf(idxf, 0.0f), 255.0f);
      float xs = -10.0f + idxf * delta;
      e = rintf((float)exp((double)xs) / EXP_SCALE_F);
    } else {
      float delta = 10.0f / 255.0f;
      float idxf = rintf((x + 20.0f) * 25.5f);
      idxf = fminf(fmaxf(idxf, 0.0f), 255.0f);
      float xs = -20.0f + idxf * delta;
      e = rintf((float)exp((double)xs) / EXP_SCALE_F);
    }
    e = fminf(fmaxf(e, -32768.0f), 32767.0f);
    exp_tab[t] = (int)e;
  }
  __syncthreads();

  const float K_F = (float)((2.0 / 65535.0) * ((1.0 / 0.1) * 2.0 / 65535.0) / (2.0 / 255.0));
  const float OUT_SCALE_F = (float)(2.0 / 255.0);

  const int total4 = NB * NC * NQ4;          // 6,553,600 int4 units
  const int4* g4 = (const int4*)data;
  vfloat4* o4 = (vfloat4*)out;

  for (int u = blockIdx.x * TPB + t; u < total4; u += gridDim.x * TPB) {
    int4 v = g4[u];                          // dense, linear
    const int quad = u % NQ4;                // hw/4 within the image plane
    const int b    = u / (NQ4 * NC);
    const int pq   = b * NQ4 + quad;
    const int qp   = qp_ws[pq];
    const float4 rv = rec_ws[pq];
    // j = qmax - v, guaranteed in [0,255] (champion-exact indexing)
    float e0 = (float)exp_tab[((qp << 24) >> 24) - v.x];
    float e1 = (float)exp_tab[((qp << 16) >> 24) - v.y];
    float e2 = (float)exp_tab[((qp << 8) >> 24) - v.z];
    float e3 = (float)exp_tab[(qp >> 24) - v.w];
    vfloat4 o;
    o.x = fminf(fmaxf(rintf((e0 * rv.x) * K_F), -128.0f), 127.0f) * OUT_SCALE_F;
    o.y = fminf(fmaxf(rintf((e1 * rv.y) * K_F), -128.0f), 127.0f) * OUT_SCALE_F;
    o.z = fminf(fmaxf(rintf((e2 * rv.z) * K_F), -128.0f), 127.0f) * OUT_SCALE_F;
    o.w = fminf(fmaxf(rintf((e3 * rv.w) * K_F), -128.0f), 127.0f) * OUT_SCALE_F;
    __builtin_nontemporal_store(o, &o4[u]);  // dense, linear; don't pollute L3
  }
}

// ---------------------------------------------------------------------------
// Fallback: the verified 65-us monolithic champion (used if ws too small).
// ---------------------------------------------------------------------------
__global__ __launch_bounds__(TPB) void qsoftmax_mono_kernel(
    const int* __restrict__ data,
    const float* __restrict__ dscale,
    float* __restrict__ out) {
#pragma clang fp contract(off)
  __shared__ int   exp_tab[256];
  __shared__ float recip_tab[256];
  __shared__ int4  red_m[16][16];
  __shared__ int4  red_s[16][16];

  const int t  = threadIdx.x;
  const int k  = t >> 4;
  const int p4 = t & 15;

  const int blk  = blockIdx.x;
  const int b    = blk / (NHW / PIX);
  const int hw0  = (blk % (NHW / PIX)) * PIX;
  const int base4 = b * NC * NQ4 + (hw0 >> 2);

  const float ds = dscale[0];

  {
    const float EXP_SCALE_F = (float)(2.0 / 65535.0);
    float x = (float)(-t) * ds;
    float e;
    if (x >= 0.0f) {
      float y0 = expf(0.0f), y1 = expf(1.0f);
      e = rintf((y0 + x * ((y1 - y0) / 1.0f)) / EXP_SCALE_F);
    } else if (x >= -10.0f) {
      float delta = 10.0f / 255.0f;
      float idxf = rintf((x + 10.0f) * 25.5f);
      idxf = fminf(fmaxf(idxf, 0.0f), 255.0f);
      float xs = -10.0f + idxf * delta;
      e = rintf((float)exp((double)xs) / EXP_SCALE_F);
    } else {
      float delta = 10.0f / 255.0f;
      float idxf = rintf((x + 20.0f) * 25.5f);
      idxf = fminf(fmaxf(idxf, 0.0f), 255.0f);
      float xs = -20.0f + idxf * delta;
      e = rintf((float)exp((double)xs) / EXP_SCALE_F);
    }
    e = fminf(fmaxf(e, -32768.0f), 32767.0f);
    exp_tab[t] = (int)e;

    const float RECIP_SCALE_F = (float)((1.0 / 0.1) * 2.0 / 65535.0);
    float deltar = (250.0f - 0.1f) / 255.0f;
    float xs = 0.1f + (float)t * deltar;
    float r = rintf((1.0f / xs) / RECIP_SCALE_F);
    r = fminf(fmaxf(r, -32768.0f), 32767.0f);
    recip_tab[t] = r;
  }

  const int4* g4 = (const int4*)data;
  int pd[8];
  int4 m = make_int4(-128, -128, -128, -128);
#pragma unroll
  for (int i = 0; i < 8; ++i) {
    int4 v = g4[base4 + (16 * i + k) * NQ4 + p4];
    m.x = max(m.x, v.x); m.y = max(m.y, v.y);
    m.z = max(m.z, v.z); m.w = max(m.w, v.w);
    pd[i] = (v.x & 255) | ((v.y & 255) << 8) | ((v.z & 255) << 16) |
            (int)((unsigned)(v.w & 255) << 24);
  }
  red_m[k][p4] = m;
  __syncthreads();

  int4 q = red_m[0][p4];
#pragma unroll
  for (int kk = 1; kk < 16; ++kk) {
    int4 r = red_m[kk][p4];
    q.x = max(q.x, r.x); q.y = max(q.y, r.y);
    q.z = max(q.z, r.z); q.w = max(q.w, r.w);
  }

  int pe[16];
  int4 s = make_int4(0, 0, 0, 0);
#pragma unroll
  for (int i = 0; i < 8; ++i) {
    int pdv = pd[i];
    int c0 = (pdv << 24) >> 24;
    int c1 = (pdv << 16) >> 24;
    int c2 = (pdv << 8) >> 24;
    int c3 = pdv >> 24;
    int e0 = exp_tab[q.x - c0];
    int e1 = exp_tab[q.y - c1];
    int e2 = exp_tab[q.z - c2];
    int e3 = exp_tab[q.w - c3];
    s.x += e0; s.y += e1; s.z += e2; s.w += e3;
    pe[2 * i]     = e0 | (e1 << 16);
    pe[2 * i + 1] = e2 | (e3 << 16);
  }
  red_s[k][p4] = s;
  __syncthreads();

  int4 tot = red_s[0][p4];
#pragma unroll
  for (int kk = 1; kk < 16; ++kk) {
    int4 r = red_s[kk][p4];
    tot.x += r.x; tot.y += r.y; tot.z += r.z; tot.w += r.w;
  }
  const float DIV_SCALE_F = (float)((2.0 / 65535.0) * 128.0);
  const float RIDX_K_F    = (float)(255.0 / (250.0 - 0.1));
  float rq[4];
  {
    int tv[4] = {tot.x, tot.y, tot.z, tot.w};
#pragma unroll
    for (int j = 0; j < 4; ++j) {
      float ss = rintf((float)tv[j] * 0.0078125f);
      ss = fminf(fmaxf(ss, -32768.0f), 32767.0f);
      float v = ss * DIV_SCALE_F;
      float idxf = rintf((v - 0.1f) * RIDX_K_F);
      idxf = fminf(fmaxf(idxf, 0.0f), 255.0f);
      rq[j] = recip_tab[(int)idxf];
    }
  }

  const float K_F = (float)((2.0 / 65535.0) * ((1.0 / 0.1) * 2.0 / 65535.0) / (2.0 / 255.0));
  const float OUT_SCALE_F = (float)(2.0 / 255.0);
  vfloat4* o4 = (vfloat4*)out;
#pragma unroll
  for (int i = 0; i < 8; ++i) {
    int pa = pe[2 * i], pb = pe[2 * i + 1];
    float e0 = (float)(pa & 0xFFFF);
    float e1 = (float)(pa >> 16);
    float e2 = (float)(pb & 0xFFFF);
    float e3 = (float)(pb >> 16);
    vfloat4 o;
    o.x = fminf(fmaxf(rintf((e0 * rq[0]) * K_F), -128.0f), 127.0f) * OUT_SCALE_F;
    o.y = fminf(fmaxf(rintf((e1 * rq[1]) * K_F), -128.0f), 127.0f) * OUT_SCALE_F;
    o.z = fminf(fmaxf(rintf((e2 * rq[2]) * K_F), -128.0f), 127.0f) * OUT_SCALE_F;
    o.w = fminf(fmaxf(rintf((e3 * rq[3]) * K_F), -128.0f), 127.0f) * OUT_SCALE_F;
    __builtin_nontemporal_store(o, &o4[base4 + (16 * i + k) * NQ4 + p4]);
  }
}

extern "C" void kernel_launch(void* const* d_in, const int* in_sizes, int n_in,
                              void* d_out, int out_size, void* d_ws, size_t ws_size,
                              hipStream_t stream) {
  const int* data     = (const int*)d_in[0];
  const float* dscale = (const float*)d_in[1];
  float* out          = (float*)d_out;
  (void)in_sizes; (void)n_in; (void)out_size;

  const size_t need = (size_t)NQUAD * 4 + (size_t)NQUAD * 16;  // 1,024,000 B
  if (d_ws != nullptr && ws_size >= need) {
    int*    qp_ws  = (int*)d_ws;                              // 51200 x int
    float4* rec_ws = (float4*)((char*)d_ws + (size_t)NQUAD * 4);
    qsoftmax_stats_kernel<<<dim3(NB * (NHW / PIX)), dim3(TPB), 0, stream>>>(
        data, dscale, qp_ws, rec_ws);
    qsoftmax_expand_kernel<<<dim3(2048), dim3(TPB), 0, stream>>>(
        data, dscale, qp_ws, rec_ws, out);
  } else {
    qsoftmax_mono_kernel<<<dim3(NB * (NHW / PIX)), dim3(TPB), 0, stream>>>(
        data, dscale, out);
  }
}

// Round 9
// 191.809 us; speedup vs baseline: 1.0450x; 1.0450x over previous
//
#include <hip/hip_runtime.h>
#include <cmath>

// Shapes fixed by the reference: data [32,128,80,80] int32, scale 0.0625.
#define NB  32
#define NC  128
#define NHW 6400          // 80*80, contiguous per (b,c)
#define PIX 64            // pixels per block
#define TPB 256           // 16 "k" channel-groups x 16 pixel-quads
#define NWG (NB * (NHW / PIX))   // 3200 workgroups, divisible by 8 XCDs

typedef float vfloat4 __attribute__((ext_vector_type(4)));

// Champion kernel + ONE change: bijective chunked XCD swizzle so that each
// XCD owns a CONTIGUOUS range of hw-tiles. Consecutive blockIdx round-robin
// across the 8 XCDs (m09); wg = (orig&7)*400 + orig>>3 gives XCD x the
// original blocks [400x, 400x+400) -> co-resident blocks on one XCD write
// ADJACENT 256B chunks of the same DRAM pages through the SAME L2, turning
// the machine-wide scattered write stream into 8 clustered sequential ones.
// Stores are PLAIN (cached) so the per-XCD L2 can merge/order the chunks
// (r2: plain vs NT standalone is <=2us and causes no read-for-ownership).

__global__ __launch_bounds__(TPB) void qsoftmax_kernel(
    const int* __restrict__ data,
    const float* __restrict__ dscale,
    float* __restrict__ out) {
#pragma clang fp contract(off)
  __shared__ int   exp_tab[256];    // quantized exp as function of j = qmax - data
  __shared__ float recip_tab[256];  // quantized 1/v table, region (0.1, 250)
  __shared__ int4  red_m[16][16];   // [k][p4] partial max
  __shared__ int4  red_s[16][16];   // [k][p4] partial sum

  const int t  = threadIdx.x;
  const int k  = t >> 4;
  const int p4 = t & 15;

  // ---- bijective chunked XCD swizzle (NWG = 3200 = 8 * 400) ----
  const int orig = blockIdx.x;
  const int blk  = (orig & 7) * (NWG / 8) + (orig >> 3);

  const int b    = blk / (NHW / PIX);
  const int hw0  = (blk % (NHW / PIX)) * PIX;
  const int base4 = b * NC * (NHW / 4) + (hw0 >> 2);   // int4 index

  const float ds = dscale[0];  // 0.0625

  // ---- build LUTs (identical math to the verified version; do not touch) ----
  {
    const float EXP_SCALE_F = (float)(2.0 / 65535.0);
    float x = (float)(-t) * ds;
    float e;
    if (x >= 0.0f) {
      float y0 = expf(0.0f), y1 = expf(1.0f);
      e = rintf((y0 + x * ((y1 - y0) / 1.0f)) / EXP_SCALE_F);
    } else if (x >= -10.0f) {
      float delta = 10.0f / 255.0f;
      float idxf = rintf((x + 10.0f) * 25.5f);
      idxf = fminf(fmaxf(idxf, 0.0f), 255.0f);
      float xs = -10.0f + idxf * delta;
      e = rintf((float)exp((double)xs) / EXP_SCALE_F);
    } else {
      float delta = 10.0f / 255.0f;
      float idxf = rintf((x + 20.0f) * 25.5f);
      idxf = fminf(fmaxf(idxf, 0.0f), 255.0f);
      float xs = -20.0f + idxf * delta;
      e = rintf((float)exp((double)xs) / EXP_SCALE_F);
    }
    e = fminf(fmaxf(e, -32768.0f), 32767.0f);
    exp_tab[t] = (int)e;

    const float RECIP_SCALE_F = (float)((1.0 / 0.1) * 2.0 / 65535.0);
    float deltar = (250.0f - 0.1f) / 255.0f;
    float xs = 0.1f + (float)t * deltar;
    float r = rintf((1.0f / xs) / RECIP_SCALE_F);
    r = fminf(fmaxf(r, -32768.0f), 32767.0f);
    recip_tab[t] = r;
  }

  // ---- load 8 channels x 4 pixels; pack to 4x int8 per int; local max ----
  const int4* g4 = (const int4*)data;
  int pd[8];                         // packed raw data, 8 VGPRs
  int4 m = make_int4(-128, -128, -128, -128);
#pragma unroll
  for (int i = 0; i < 8; ++i) {
    int4 v = g4[base4 + (16 * i + k) * (NHW / 4) + p4];
    m.x = max(m.x, v.x); m.y = max(m.y, v.y);
    m.z = max(m.z, v.z); m.w = max(m.w, v.w);
    pd[i] = (v.x & 255) | ((v.y & 255) << 8) | ((v.z & 255) << 16) |
            (int)((unsigned)(v.w & 255) << 24);
  }
  red_m[k][p4] = m;
  __syncthreads();

  // ---- every thread reduces the 16 partial maxes (broadcast b128 reads) ----
  int4 q = red_m[0][p4];
#pragma unroll
  for (int kk = 1; kk < 16; ++kk) {
    int4 r = red_m[kk][p4];
    q.x = max(q.x, r.x); q.y = max(q.y, r.y);
    q.z = max(q.z, r.z); q.w = max(q.w, r.w);
  }

  // ---- exp LUT gather + pack exp (u16 pairs) + channel partial sum ----
  int pe[16];                        // packed exp, 16 VGPRs
  int4 s = make_int4(0, 0, 0, 0);
#pragma unroll
  for (int i = 0; i < 8; ++i) {
    int pdv = pd[i];
    int c0 = (pdv << 24) >> 24;
    int c1 = (pdv << 16) >> 24;
    int c2 = (pdv << 8) >> 24;
    int c3 = pdv >> 24;
    int e0 = exp_tab[q.x - c0];      // j guaranteed in [0,255]
    int e1 = exp_tab[q.y - c1];
    int e2 = exp_tab[q.z - c2];
    int e3 = exp_tab[q.w - c3];
    s.x += e0; s.y += e1; s.z += e2; s.w += e3;
    pe[2 * i]     = e0 | (e1 << 16); // e in [0,32767] -> fits u16, sign-safe
    pe[2 * i + 1] = e2 | (e3 << 16);
  }
  red_s[k][p4] = s;
  __syncthreads();

  // ---- every thread reduces the 16 partial sums, then recip (redundant) ----
  int4 tot = red_s[0][p4];
#pragma unroll
  for (int kk = 1; kk < 16; ++kk) {
    int4 r = red_s[kk][p4];
    tot.x += r.x; tot.y += r.y; tot.z += r.z; tot.w += r.w;
  }
  const float DIV_SCALE_F = (float)((2.0 / 65535.0) * 128.0); // exp_scale * 2^7
  const float RIDX_K_F    = (float)(255.0 / (250.0 - 0.1));
  float rq[4];
  {
    int tv[4] = {tot.x, tot.y, tot.z, tot.w};
#pragma unroll
    for (int j = 0; j < 4; ++j) {
      float ss = rintf((float)tv[j] * 0.0078125f);
      ss = fminf(fmaxf(ss, -32768.0f), 32767.0f);
      float v = ss * DIV_SCALE_F;
      float idxf = rintf((v - 0.1f) * RIDX_K_F);
      idxf = fminf(fmaxf(idxf, 0.0f), 255.0f);
      rq[j] = recip_tab[(int)idxf];
    }
  }

  // ---- epilogue: out = clip(round((e*r)*K), -128, 127) * OUT_SCALE ----
  const float K_F = (float)((2.0 / 65535.0) * ((1.0 / 0.1) * 2.0 / 65535.0) / (2.0 / 255.0));
  const float OUT_SCALE_F = (float)(2.0 / 255.0);
  vfloat4* o4 = (vfloat4*)out;
#pragma unroll
  for (int i = 0; i < 8; ++i) {
    int pa = pe[2 * i], pb = pe[2 * i + 1];
    float e0 = (float)(pa & 0xFFFF);
    float e1 = (float)(pa >> 16);
    float e2 = (float)(pb & 0xFFFF);
    float e3 = (float)(pb >> 16);
    vfloat4 o;
    o.x = fminf(fmaxf(rintf((e0 * rq[0]) * K_F), -128.0f), 127.0f) * OUT_SCALE_F;
    o.y = fminf(fmaxf(rintf((e1 * rq[1]) * K_F), -128.0f), 127.0f) * OUT_SCALE_F;
    o.z = fminf(fmaxf(rintf((e2 * rq[2]) * K_F), -128.0f), 127.0f) * OUT_SCALE_F;
    o.w = fminf(fmaxf(rintf((e3 * rq[3]) * K_F), -128.0f), 127.0f) * OUT_SCALE_F;
    o4[base4 + (16 * i + k) * (NHW / 4) + p4] = o;   // plain store -> L2 merge
  }
}

extern "C" void kernel_launch(void* const* d_in, const int* in_sizes, int n_in,
                              void* d_out, int out_size, void* d_ws, size_t ws_size,
                              hipStream_t stream) {
  const int* data     = (const int*)d_in[0];
  const float* dscale = (const float*)d_in[1];
  float* out          = (float*)d_out;
  (void)in_sizes; (void)n_in; (void)d_ws; (void)ws_size; (void)out_size;

  dim3 grid(NWG);   // 3200 blocks
  qsoftmax_kernel<<<grid, TPB, 0, stream>>>(data, dscale, out);
}